// Round 1
// baseline (142.861 us; speedup 1.0000x reference)
//
#include <hip/hip_runtime.h>
#include <stdint.h>

#define H_ 4
#define N_ 512
#define D_ 64
#define E_ (N_ * N_)        // 262144 edges per head
#define HE_ (H_ * E_)       // 1048576 (also == threefry half-size for scheme 2)
#define EPS_ 1e-10f

// RNG scheme: 1 = partitionable threefry (JAX >= 0.5 default):
//                 per-element u64 counter (hi=0, lo=j), 32-bit out = x0 ^ x1
//             2 = original threefry: counters = iota split in halves
#define RNG_SCHEME 1

__device__ __forceinline__ void tf2x32(unsigned x0, unsigned x1,
                                       unsigned& o0, unsigned& o1) {
  const unsigned ks0 = 0u;          // key hi of seed 42
  const unsigned ks1 = 42u;         // key lo
  const unsigned ks2 = 0x1BD11BDAu ^ ks0 ^ ks1;
  x0 += ks0; x1 += ks1;
#define TFR(r) { x0 += x1; x1 = (x1 << (r)) | (x1 >> (32 - (r))); x1 ^= x0; }
  TFR(13) TFR(15) TFR(26) TFR(6)
  x0 += ks1; x1 += ks2 + 1u;
  TFR(17) TFR(29) TFR(16) TFR(24)
  x0 += ks2; x1 += ks0 + 2u;
  TFR(13) TFR(15) TFR(26) TFR(6)
  x0 += ks0; x1 += ks1 + 3u;
  TFR(17) TFR(29) TFR(16) TFR(24)
  x0 += ks1; x1 += ks2 + 4u;
  TFR(13) TFR(15) TFR(26) TFR(6)
  x0 += ks2; x1 += ks0 + 5u;
#undef TFR
  o0 = x0; o1 = x1;
}

__device__ __forceinline__ unsigned rng_bits(unsigned j) {
  unsigned a, b;
#if RNG_SCHEME == 1
  tf2x32(0u, j, a, b);           // counter = (uint64)j split hi/lo
  return a ^ b;
#else
  if (j < (unsigned)HE_) { tf2x32(j, j + (unsigned)HE_, a, b); return a; }
  else                   { tf2x32(j - (unsigned)HE_, j, a, b); return b; }
#endif
}

__device__ __forceinline__ float u01(unsigned bits) {
  // jax _uniform: bitcast((bits >> 9) | 0x3f800000) - 1.0
  return __uint_as_float((bits >> 9) | 0x3f800000u) - 1.0f;
}

// ---------------- node projection: A = feats@W_out[:64], B = feats@W_out[64:]
__global__ __launch_bounds__(256) void precompute_ab(
    const float* __restrict__ feats, const float* __restrict__ W_out,
    float* __restrict__ A, float* __restrict__ B) {
  int row = blockIdx.x * 4 + (threadIdx.x >> 6);   // h*N + n
  int d = threadIdx.x & 63;
  __shared__ float f[4][64];
  f[threadIdx.x >> 6][d] = feats[row * D_ + d];
  __syncthreads();
  const float* fr = f[threadIdx.x >> 6];
  float a = 0.f, b = 0.f;
#pragma unroll 8
  for (int k = 0; k < D_; ++k) {
    float fv = fr[k];
    a = fmaf(fv, W_out[k * D_ + d], a);          // sender rows [0,64)
    b = fmaf(fv, W_out[(k + D_) * D_ + d], b);   // receiver rows [64,128)
  }
  A[row * D_ + d] = a;
  B[row * D_ + d] = b;
}

// ---------------- fused edge kernel: logits, gumbel hard decision, prob
__global__ __launch_bounds__(256) void edge_kernel(
    const float* __restrict__ A, const float* __restrict__ B,
    const float* __restrict__ b_out, const float* __restrict__ W_cat,
    const float* __restrict__ b_cat, float* __restrict__ out) {
  __shared__ float Ash[64][65];   // stride 65: inner reads are 2-way aliased (free)
  __shared__ float Bsh[16][64];   // broadcast reads
  __shared__ float bsh[64];
  __shared__ float wc[128];
  __shared__ float bc[2];

  const int t = threadIdx.x;
  const int h = blockIdx.z;
  const int snd_base = blockIdx.x * 64;
  const int rec_base = blockIdx.y * 16;

  for (int i = t; i < 4096; i += 256) {
    int r = i >> 6, c = i & 63;
    Ash[r][c] = A[(h * N_ + snd_base + r) * D_ + c];
  }
  for (int i = t; i < 1024; i += 256) {
    int r = i >> 6, c = i & 63;
    Bsh[r][c] = B[(h * N_ + rec_base + r) * D_ + c];
  }
  if (t < 64) bsh[t] = b_out[t];
  if (t >= 64 && t < 192) wc[t - 64] = W_cat[t - 64];
  if (t == 192) { bc[0] = b_cat[0]; bc[1] = b_cat[1]; }
  __syncthreads();

  const int s = t & 63;            // sender within tile (lane-varying)
  const int rg = (t >> 6) * 4;     // 4 receivers per thread (wave-uniform)

  for (int r = 0; r < 4; ++r) {
    const int rl = rg + r;
    float l0 = 0.f, l1 = 0.f;
#pragma unroll 8
    for (int d = 0; d < D_; ++d) {
      float tv = Ash[s][d] + Bsh[rl][d] + bsh[d];
      tv = fmaxf(tv, 0.f);
      l0 = fmaf(tv, wc[2 * d], l0);
      l1 = fmaf(tv, wc[2 * d + 1], l1);
    }
    l0 += bc[0]; l1 += bc[1];

    const unsigned e = (unsigned)(rec_base + rl) * N_ + (unsigned)(snd_base + s);
    const unsigned base = ((unsigned)h << 18) + e;   // h*E + e  (E = 2^18)
    const unsigned j0 = base * 2u;                   // flat idx into [H,E,2]

    float uu0 = u01(rng_bits(j0));
    float uu1 = u01(rng_bits(j0 + 1u));
    float g0 = -logf(-logf(uu0 + EPS_) + EPS_);
    float g1 = -logf(-logf(uu1 + EPS_) + EPS_);

    // y_soft = softmax((logits+g)/0.5); hard decision mimics fp rounding
    float a0 = (l0 + g0) / 0.5f;
    float a1 = (l1 + g1) / 0.5f;
    float am = fmaxf(a0, a1);
    float ea0 = expf(a0 - am), ea1 = expf(a1 - am);
    float ss = ea0 + ea1;
    float cm = ((ea1 / ss) > (ea0 / ss)) ? 1.0f : 0.0f;

    // connection_prob = softmax(logits)[...,1]
    float lm = fmaxf(l0, l1);
    float p0 = expf(l0 - lm), p1 = expf(l1 - lm);
    float pr = p1 / (p0 + p1);

    out[base] = cm;                 // connection_matrix
    out[HE_ + base] = pr;           // connection_prob
    out[2 * HE_ + base] = 0.f;      // sparse_labels zero-init (stage3 sets ones)
  }
}

// ---------------- exact top-64 per head: 3-stage bitonic partial selection
__device__ __forceinline__ void bitonic1024(unsigned long long* keys) {
  const int t = threadIdx.x;
  for (int k = 2; k <= 1024; k <<= 1) {
    for (int j = k >> 1; j > 0; j >>= 1) {
      int ixj = t ^ j;
      if (ixj > t) {
        unsigned long long a = keys[t], b = keys[ixj];
        bool up = (t & k) == 0;
        if ((a > b) == up) { keys[t] = b; keys[ixj] = a; }
      }
      __syncthreads();
    }
  }
}

__global__ __launch_bounds__(1024) void topk_stage1(
    const float* __restrict__ prob, unsigned long long* __restrict__ cand) {
  __shared__ unsigned long long keys[1024];
  const int t = threadIdx.x, h = blockIdx.y, blk = blockIdx.x;
  const unsigned idx = blk * 1024u + t;
  float p = prob[(unsigned)h * E_ + idx];
  // larger key = larger prob; among equal probs, smaller idx wins (ties as lax.top_k)
  keys[t] = ((unsigned long long)__float_as_uint(p) << 32) | (unsigned)(~idx);
  __syncthreads();
  bitonic1024(keys);
  if (t >= 960) cand[h * 16384 + blk * 64 + (t - 960)] = keys[t];
}

__global__ __launch_bounds__(1024) void topk_stage2(
    const unsigned long long* __restrict__ cand1,
    unsigned long long* __restrict__ cand2) {
  __shared__ unsigned long long keys[1024];
  const int t = threadIdx.x, h = blockIdx.y, blk = blockIdx.x;
  keys[t] = cand1[h * 16384 + blk * 1024 + t];
  __syncthreads();
  bitonic1024(keys);
  if (t >= 960) cand2[h * 1024 + blk * 64 + (t - 960)] = keys[t];
}

__global__ __launch_bounds__(1024) void topk_stage3(
    const unsigned long long* __restrict__ cand2, float* __restrict__ sparse) {
  __shared__ unsigned long long keys[1024];
  const int t = threadIdx.x, h = blockIdx.y;
  keys[t] = cand2[h * 1024 + t];
  __syncthreads();
  bitonic1024(keys);
  if (t >= 960) {
    unsigned idx = ~(unsigned)(keys[t] & 0xFFFFFFFFull);
    sparse[(unsigned)h * E_ + idx] = 1.0f;
  }
}

extern "C" void kernel_launch(void* const* d_in, const int* in_sizes, int n_in,
                              void* d_out, int out_size, void* d_ws, size_t ws_size,
                              hipStream_t stream) {
  const float* feats = (const float*)d_in[0];
  const float* W_out = (const float*)d_in[1];
  const float* b_out = (const float*)d_in[2];
  const float* W_cat = (const float*)d_in[3];
  const float* b_cat = (const float*)d_in[4];
  float* out = (float*)d_out;

  // workspace layout (~1.6 MB): A | B | cand1 | cand2
  float* A = (float*)d_ws;
  float* B = A + H_ * N_ * D_;
  unsigned long long* cand1 = (unsigned long long*)(B + H_ * N_ * D_);
  unsigned long long* cand2 = cand1 + H_ * 16384;

  precompute_ab<<<dim3(H_ * N_ / 4), dim3(256), 0, stream>>>(feats, W_out, A, B);
  edge_kernel<<<dim3(N_ / 64, N_ / 16, H_), dim3(256), 0, stream>>>(
      A, B, b_out, W_cat, b_cat, out);
  topk_stage1<<<dim3(E_ / 1024, H_), dim3(1024), 0, stream>>>(out + HE_, cand1);
  topk_stage2<<<dim3(16, H_), dim3(1024), 0, stream>>>(cand1, cand2);
  topk_stage3<<<dim3(1, H_), dim3(1024), 0, stream>>>(cand2, out + 2 * HE_);
}

// Round 2
// 111.180 us; speedup vs baseline: 1.2849x; 1.2849x over previous
//
#include <hip/hip_runtime.h>
#include <stdint.h>

#define H_ 4
#define N_ 512
#define D_ 64
#define E_ (N_ * N_)        // 262144 edges per head
#define HE_ (H_ * E_)       // 1048576
#define EPS_ 1e-10f

// RNG scheme 1 (verified by round-1 pass): partitionable threefry,
// per-element u64 counter (hi=0, lo=j), 32-bit out = x0 ^ x1.
__device__ __forceinline__ void tf2x32(unsigned x0, unsigned x1,
                                       unsigned& o0, unsigned& o1) {
  const unsigned ks0 = 0u;          // key hi of seed 42
  const unsigned ks1 = 42u;         // key lo
  const unsigned ks2 = 0x1BD11BDAu ^ ks0 ^ ks1;
  x0 += ks0; x1 += ks1;
#define TFR(r) { x0 += x1; x1 = (x1 << (r)) | (x1 >> (32 - (r))); x1 ^= x0; }
  TFR(13) TFR(15) TFR(26) TFR(6)
  x0 += ks1; x1 += ks2 + 1u;
  TFR(17) TFR(29) TFR(16) TFR(24)
  x0 += ks2; x1 += ks0 + 2u;
  TFR(13) TFR(15) TFR(26) TFR(6)
  x0 += ks0; x1 += ks1 + 3u;
  TFR(17) TFR(29) TFR(16) TFR(24)
  x0 += ks1; x1 += ks2 + 4u;
  TFR(13) TFR(15) TFR(26) TFR(6)
  x0 += ks2; x1 += ks0 + 5u;
#undef TFR
  o0 = x0; o1 = x1;
}

__device__ __forceinline__ unsigned rng_bits(unsigned j) {
  unsigned a, b;
  tf2x32(0u, j, a, b);
  return a ^ b;
}

__device__ __forceinline__ float u01(unsigned bits) {
  return __uint_as_float((bits >> 9) | 0x3f800000u) - 1.0f;
}

// ---------------- node projection: A = feats@W_out[:64], B = feats@W_out[64:]
__global__ __launch_bounds__(256) void precompute_ab(
    const float* __restrict__ feats, const float* __restrict__ W_out,
    float* __restrict__ A, float* __restrict__ B) {
  int row = blockIdx.x * 4 + (threadIdx.x >> 6);   // h*N + n
  int d = threadIdx.x & 63;
  __shared__ float f[4][64];
  f[threadIdx.x >> 6][d] = feats[row * D_ + d];
  __syncthreads();
  const float* fr = f[threadIdx.x >> 6];
  float a = 0.f, b = 0.f;
#pragma unroll 8
  for (int k = 0; k < D_; ++k) {
    float fv = fr[k];
    a = fmaf(fv, W_out[k * D_ + d], a);          // sender rows [0,64)
    b = fmaf(fv, W_out[(k + D_) * D_ + d], b);   // receiver rows [64,128)
  }
  A[row * D_ + d] = a;
  B[row * D_ + d] = b;
}

// ---------------- fused edge kernel: 128 snd x 16 rec tile, 8 edges/thread
__global__ __launch_bounds__(256) void edge_kernel(
    const float* __restrict__ A, const float* __restrict__ B,
    const float* __restrict__ b_out, const float* __restrict__ W_cat,
    const float* __restrict__ b_cat, float* __restrict__ out,
    unsigned long long* __restrict__ blockmax) {
  __shared__ float Ash[128][65];   // stride 65: per-lane reads 2-way aliased (free)
  __shared__ float Bsh[16][64];
  __shared__ float bsh[64];
  __shared__ float2 wc2[64];
  __shared__ float bc2[2];
  __shared__ unsigned long long wmax[4];

  const int t = threadIdx.x;
  const int h = blockIdx.z;
  const int snd_base = blockIdx.x * 128;
  const int rec_base = blockIdx.y * 16;

  const float4* A4 = (const float4*)(A + (h * N_ + snd_base) * D_);
  for (int i = t; i < 2048; i += 256) {
    float4 v = A4[i];
    int r = i >> 4, c = (i & 15) * 4;
    Ash[r][c] = v.x; Ash[r][c + 1] = v.y; Ash[r][c + 2] = v.z; Ash[r][c + 3] = v.w;
  }
  {
    const float4* B4 = (const float4*)(B + (h * N_ + rec_base) * D_);
    float4 v = B4[t];
    int r = t >> 4, c = (t & 15) * 4;
    *(float4*)&Bsh[r][c] = v;
  }
  if (t < 64) { bsh[t] = b_out[t]; wc2[t] = ((const float2*)W_cat)[t]; }
  if (t == 64) { bc2[0] = b_cat[0]; bc2[1] = b_cat[1]; }
  __syncthreads();

  const int s = t & 63;            // sender lane (per-lane varying)
  const int rg = (t >> 6) * 4;     // receiver group (wave-uniform)

  float l0[2][4], l1[2][4];
#pragma unroll
  for (int q = 0; q < 2; ++q)
#pragma unroll
    for (int r = 0; r < 4; ++r) { l0[q][r] = 0.f; l1[q][r] = 0.f; }

#pragma unroll 4
  for (int d = 0; d < 64; ++d) {
    float a0 = Ash[s][d];
    float a1 = Ash[s + 64][d];
    float bd = bsh[d];
    float2 w = wc2[d];
#pragma unroll
    for (int r = 0; r < 4; ++r) {
      float bv = Bsh[rg + r][d];
      // bit-identical to round-1: ((A + B) + b), then relu, then fma chain d=0..63
      float t0 = fmaxf((a0 + bv) + bd, 0.f);
      float t1 = fmaxf((a1 + bv) + bd, 0.f);
      l0[0][r] = fmaf(t0, w.x, l0[0][r]);
      l1[0][r] = fmaf(t0, w.y, l1[0][r]);
      l0[1][r] = fmaf(t1, w.x, l0[1][r]);
      l1[1][r] = fmaf(t1, w.y, l1[1][r]);
    }
  }

  unsigned long long mk = 0ull;
#pragma unroll
  for (int q = 0; q < 2; ++q) {
#pragma unroll
    for (int r = 0; r < 4; ++r) {
      float L0 = l0[q][r] + bc2[0];
      float L1 = l1[q][r] + bc2[1];
      const unsigned snd = (unsigned)(snd_base + s + q * 64);
      const unsigned rec = (unsigned)(rec_base + rg + r);
      const unsigned e = rec * (unsigned)N_ + snd;
      const unsigned base = ((unsigned)h << 18) + e;
      const unsigned j0 = base * 2u;

      float uu0 = u01(rng_bits(j0));
      float uu1 = u01(rng_bits(j0 + 1u));
      float g0 = -logf(-logf(uu0 + EPS_) + EPS_);
      float g1 = -logf(-logf(uu1 + EPS_) + EPS_);

      float A0 = (L0 + g0) / 0.5f;
      float A1 = (L1 + g1) / 0.5f;
      float am = fmaxf(A0, A1);
      float ea0 = expf(A0 - am), ea1 = expf(A1 - am);
      float ss2 = ea0 + ea1;
      float cm = ((ea1 / ss2) > (ea0 / ss2)) ? 1.0f : 0.0f;

      float lm = fmaxf(L0, L1);
      float p0 = expf(L0 - lm), p1 = expf(L1 - lm);
      float pr = p1 / (p0 + p1);

      out[base] = cm;
      out[HE_ + base] = pr;
      out[2 * HE_ + base] = 0.f;     // sparse_labels zero-init

      unsigned long long key =
          ((unsigned long long)__float_as_uint(pr) << 32) | (unsigned)(~e);
      mk = key > mk ? key : mk;
    }
  }

  // block max of 1024 edge keys -> blockmax[h][bid]
#pragma unroll
  for (int off = 32; off; off >>= 1) {
    unsigned long long o = __shfl_xor(mk, off, 64);
    mk = o > mk ? o : mk;
  }
  if ((t & 63) == 0) wmax[t >> 6] = mk;
  __syncthreads();
  if (t == 0) {
    unsigned long long m = wmax[0];
#pragma unroll
    for (int i = 1; i < 4; ++i) m = wmax[i] > m ? wmax[i] : m;
    blockmax[h * 128 + blockIdx.y * gridDim.x + blockIdx.x] = m;
  }
}

// ---------------- threshold: 64th largest of 128 chunk-maxes per head
__global__ __launch_bounds__(128) void select_thresh(
    const unsigned long long* __restrict__ blockmax,
    unsigned long long* __restrict__ M64, unsigned* __restrict__ cnt) {
  __shared__ unsigned long long keys[128];
  const int t = threadIdx.x, h = blockIdx.x;
  keys[t] = blockmax[h * 128 + t];
  __syncthreads();
  for (int k = 2; k <= 128; k <<= 1)
    for (int j = k >> 1; j > 0; j >>= 1) {
      int ixj = t ^ j;
      if (ixj > t) {
        unsigned long long a = keys[t], b = keys[ixj];
        bool up = (t & k) == 0;
        if ((a > b) == up) { keys[t] = b; keys[ixj] = a; }
      }
      __syncthreads();
    }
  if (t == 0) { M64[h] = keys[64]; cnt[h] = 0u; }  // 64th largest (ascending sort)
}

// ---------------- compact: keep keys >= M64 (expected ~177/head, buffer 512)
__global__ __launch_bounds__(1024) void compact(
    const float* __restrict__ prob, const unsigned long long* __restrict__ M64,
    unsigned* __restrict__ cnt, unsigned long long* __restrict__ cand) {
  const int h = blockIdx.y;
  const unsigned i4 = (blockIdx.x * 1024u + threadIdx.x) * 4u;
  const unsigned long long thr = M64[h];
  float4 p = *(const float4*)(prob + (unsigned)h * E_ + i4);
  float pv[4] = {p.x, p.y, p.z, p.w};
#pragma unroll
  for (int k = 0; k < 4; ++k) {
    unsigned e = i4 + (unsigned)k;
    unsigned long long key =
        ((unsigned long long)__float_as_uint(pv[k]) << 32) | (unsigned)(~e);
    if (key >= thr) {
      unsigned pos = atomicAdd(&cnt[h], 1u);
      if (pos < 512u) cand[h * 512 + pos] = key;
    }
  }
}

// ---------------- final: bitonic-512 over candidates, scatter 64 ones
__global__ __launch_bounds__(512) void final_topk(
    const unsigned long long* __restrict__ cand, const unsigned* __restrict__ cnt,
    float* __restrict__ sparse) {
  __shared__ unsigned long long keys[512];
  const int t = threadIdx.x, h = blockIdx.x;
  unsigned n = cnt[h]; if (n > 512u) n = 512u;
  keys[t] = (t < (int)n) ? cand[h * 512 + t] : 0ull;
  __syncthreads();
  for (int k = 2; k <= 512; k <<= 1)
    for (int j = k >> 1; j > 0; j >>= 1) {
      int ixj = t ^ j;
      if (ixj > t) {
        unsigned long long a = keys[t], b = keys[ixj];
        bool up = (t & k) == 0;
        if ((a > b) == up) { keys[t] = b; keys[ixj] = a; }
      }
      __syncthreads();
    }
  if (t >= 448) {                       // top 64 of ascending sort
    unsigned e = ~(unsigned)(keys[t] & 0xFFFFFFFFull);
    if (e < (unsigned)E_) sparse[(unsigned)h * E_ + e] = 1.0f;
  }
}

extern "C" void kernel_launch(void* const* d_in, const int* in_sizes, int n_in,
                              void* d_out, int out_size, void* d_ws, size_t ws_size,
                              hipStream_t stream) {
  const float* feats = (const float*)d_in[0];
  const float* W_out = (const float*)d_in[1];
  const float* b_out = (const float*)d_in[2];
  const float* W_cat = (const float*)d_in[3];
  const float* b_cat = (const float*)d_in[4];
  float* out = (float*)d_out;

  // workspace: A | B | blockmax | M64 | cand | cnt   (~1.07 MB)
  float* A = (float*)d_ws;
  float* B = A + H_ * N_ * D_;
  unsigned long long* blockmax = (unsigned long long*)(B + H_ * N_ * D_);
  unsigned long long* M64 = blockmax + H_ * 128;
  unsigned long long* cand = M64 + H_;
  unsigned* cnt = (unsigned*)(cand + H_ * 512);

  precompute_ab<<<dim3(H_ * N_ / 4), dim3(256), 0, stream>>>(feats, W_out, A, B);
  edge_kernel<<<dim3(N_ / 128, N_ / 16, H_), dim3(256), 0, stream>>>(
      A, B, b_out, W_cat, b_cat, out, blockmax);
  select_thresh<<<dim3(H_), dim3(128), 0, stream>>>(blockmax, M64, cnt);
  compact<<<dim3(E_ / 4096, H_), dim3(1024), 0, stream>>>(out + HE_, M64, cnt, cand);
  final_topk<<<dim3(H_), dim3(512), 0, stream>>>(cand, cnt, out + 2 * HE_);
}

// Round 3
// 110.794 us; speedup vs baseline: 1.2894x; 1.0035x over previous
//
#include <hip/hip_runtime.h>
#include <stdint.h>

#define H_ 4
#define N_ 512
#define D_ 64
#define E_ (N_ * N_)        // 262144 edges per head
#define HE_ (H_ * E_)       // 1048576
#define EPS_ 1e-10f

// Partitionable threefry (verified rounds 1-2): counter (hi=0, lo=j), out = x0^x1.
__device__ __forceinline__ void tf2x32(unsigned x0, unsigned x1,
                                       unsigned& o0, unsigned& o1) {
  const unsigned ks0 = 0u;          // key hi of seed 42
  const unsigned ks1 = 42u;         // key lo
  const unsigned ks2 = 0x1BD11BDAu ^ ks0 ^ ks1;
  x0 += ks0; x1 += ks1;
#define TFR(r) { x0 += x1; x1 = (x1 << (r)) | (x1 >> (32 - (r))); x1 ^= x0; }
  TFR(13) TFR(15) TFR(26) TFR(6)
  x0 += ks1; x1 += ks2 + 1u;
  TFR(17) TFR(29) TFR(16) TFR(24)
  x0 += ks2; x1 += ks0 + 2u;
  TFR(13) TFR(15) TFR(26) TFR(6)
  x0 += ks0; x1 += ks1 + 3u;
  TFR(17) TFR(29) TFR(16) TFR(24)
  x0 += ks1; x1 += ks2 + 4u;
  TFR(13) TFR(15) TFR(26) TFR(6)
  x0 += ks2; x1 += ks0 + 5u;
#undef TFR
  o0 = x0; o1 = x1;
}

__device__ __forceinline__ unsigned rng_bits(unsigned j) {
  unsigned a, b;
  tf2x32(0u, j, a, b);
  return a ^ b;
}

__device__ __forceinline__ float u01(unsigned bits) {
  return __uint_as_float((bits >> 9) | 0x3f800000u) - 1.0f;
}

// ---------------- node projection + zero-init of topk control words
__global__ __launch_bounds__(256) void precompute_ab(
    const float* __restrict__ feats, const float* __restrict__ W_out,
    float* __restrict__ A, float* __restrict__ B,
    unsigned* __restrict__ cnt, unsigned* __restrict__ done) {
  int row = blockIdx.x * 4 + (threadIdx.x >> 6);   // h*N + n
  int d = threadIdx.x & 63;
  if (blockIdx.x == 0) {            // ws is poisoned 0xAA each call: zero control
    if (threadIdx.x < 4) cnt[threadIdx.x] = 0u;
    else if (threadIdx.x < 8) done[threadIdx.x - 4] = 0u;
  }
  __shared__ float f[4][64];
  f[threadIdx.x >> 6][d] = feats[row * D_ + d];
  __syncthreads();
  const float* fr = f[threadIdx.x >> 6];
  float a = 0.f, b = 0.f;
#pragma unroll 8
  for (int k = 0; k < D_; ++k) {
    float fv = fr[k];
    a = fmaf(fv, W_out[k * D_ + d], a);          // sender rows [0,64)
    b = fmaf(fv, W_out[(k + D_) * D_ + d], b);   // receiver rows [64,128)
  }
  A[row * D_ + d] = a;
  B[row * D_ + d] = b;
}

// ---------------- fused edge kernel: 128 snd x 16 rec tile, 8 edges/thread
__global__ __launch_bounds__(256) void edge_kernel(
    const float* __restrict__ A, const float* __restrict__ B,
    const float* __restrict__ b_out, const float* __restrict__ W_cat,
    const float* __restrict__ b_cat, float* __restrict__ out,
    unsigned long long* __restrict__ blockmax) {
  // stride 68 floats = 272 B: rows 16B-aligned so ds_read_b128 works;
  // b128 bank spread is exactly even (each bank 8 hits = the 1KB floor).
  __shared__ __align__(16) float Ash[128][68];
  __shared__ __align__(16) float Bsh[16][64];
  __shared__ float4 bsh4[16];
  __shared__ float4 wc4[32];        // W_cat as float4: {wx[2k],wy[2k],wx[2k+1],wy[2k+1]}
  __shared__ float bc2[2];
  __shared__ unsigned long long wmax[4];

  const int t = threadIdx.x;
  const int h = blockIdx.z;
  const int snd_base = blockIdx.x * 128;
  const int rec_base = blockIdx.y * 16;

  {
    const float4* A4 = (const float4*)(A + (h * N_ + snd_base) * D_);
    for (int i = t; i < 2048; i += 256) {        // 128 rows x 16 float4
      float4 v = A4[i];
      *(float4*)&Ash[i >> 4][(i & 15) << 2] = v;
    }
    const float4* B4 = (const float4*)(B + (h * N_ + rec_base) * D_);
    float4 v = B4[t];                             // 16 rows x 16 float4 = 256
    *(float4*)&Bsh[t >> 4][(t & 15) << 2] = v;
  }
  if (t < 16) bsh4[t] = ((const float4*)b_out)[t];
  else if (t < 48) wc4[t - 16] = ((const float4*)W_cat)[t - 16];
  else if (t == 48) { bc2[0] = b_cat[0]; bc2[1] = b_cat[1]; }
  __syncthreads();

  const int s = t & 63;            // sender lane (per-lane varying)
  const int rg = (t >> 6) * 4;     // receiver group (wave-uniform)

  float l0[2][4], l1[2][4];
#pragma unroll
  for (int q = 0; q < 2; ++q)
#pragma unroll
    for (int r = 0; r < 4; ++r) { l0[q][r] = 0.f; l1[q][r] = 0.f; }

  // Per edge the fp chain is EXACTLY: for d=0..63 { t=relu((A+B)+b); l=fma(t,w,l) }
#pragma unroll
  for (int d4 = 0; d4 < 16; ++d4) {
    const float4 a0 = *(const float4*)&Ash[s][d4 << 2];
    const float4 a1 = *(const float4*)&Ash[s + 64][d4 << 2];
    const float4 bd = bsh4[d4];
    const float4 wA = wc4[2 * d4];
    const float4 wB = wc4[2 * d4 + 1];
#pragma unroll
    for (int r = 0; r < 4; ++r) {
      const float4 bv = *(const float4*)&Bsh[rg + r][d4 << 2];
      float t0, t1;
      t0 = fmaxf((a0.x + bv.x) + bd.x, 0.f);
      t1 = fmaxf((a1.x + bv.x) + bd.x, 0.f);
      l0[0][r] = fmaf(t0, wA.x, l0[0][r]); l1[0][r] = fmaf(t0, wA.y, l1[0][r]);
      l0[1][r] = fmaf(t1, wA.x, l0[1][r]); l1[1][r] = fmaf(t1, wA.y, l1[1][r]);
      t0 = fmaxf((a0.y + bv.y) + bd.y, 0.f);
      t1 = fmaxf((a1.y + bv.y) + bd.y, 0.f);
      l0[0][r] = fmaf(t0, wA.z, l0[0][r]); l1[0][r] = fmaf(t0, wA.w, l1[0][r]);
      l0[1][r] = fmaf(t1, wA.z, l0[1][r]); l1[1][r] = fmaf(t1, wA.w, l1[1][r]);
      t0 = fmaxf((a0.z + bv.z) + bd.z, 0.f);
      t1 = fmaxf((a1.z + bv.z) + bd.z, 0.f);
      l0[0][r] = fmaf(t0, wB.x, l0[0][r]); l1[0][r] = fmaf(t0, wB.y, l1[0][r]);
      l0[1][r] = fmaf(t1, wB.x, l0[1][r]); l1[1][r] = fmaf(t1, wB.y, l1[1][r]);
      t0 = fmaxf((a0.w + bv.w) + bd.w, 0.f);
      t1 = fmaxf((a1.w + bv.w) + bd.w, 0.f);
      l0[0][r] = fmaf(t0, wB.z, l0[0][r]); l1[0][r] = fmaf(t0, wB.w, l1[0][r]);
      l0[1][r] = fmaf(t1, wB.z, l0[1][r]); l1[1][r] = fmaf(t1, wB.w, l1[1][r]);
    }
  }

  unsigned long long mk = 0ull;
#pragma unroll
  for (int q = 0; q < 2; ++q) {
#pragma unroll
    for (int r = 0; r < 4; ++r) {
      float L0 = l0[q][r] + bc2[0];
      float L1 = l1[q][r] + bc2[1];
      const unsigned snd = (unsigned)(snd_base + s + q * 64);
      const unsigned rec = (unsigned)(rec_base + rg + r);
      const unsigned e = rec * (unsigned)N_ + snd;
      const unsigned base = ((unsigned)h << 18) + e;
      const unsigned j0 = base * 2u;

      float uu0 = u01(rng_bits(j0));
      float uu1 = u01(rng_bits(j0 + 1u));
      float g0 = -logf(-logf(uu0 + EPS_) + EPS_);
      float g1 = -logf(-logf(uu1 + EPS_) + EPS_);

      // argmax(softmax((l+g)/0.5)) == (L1+g1 > L0+g0): /0.5 exact, softmax monotone
      float cm = ((L1 + g1) > (L0 + g0)) ? 1.0f : 0.0f;

      float lm = fmaxf(L0, L1);
      float p0 = expf(L0 - lm), p1 = expf(L1 - lm);
      float pr = p1 / (p0 + p1);

      out[base] = cm;
      out[HE_ + base] = pr;
      out[2 * HE_ + base] = 0.f;     // sparse_labels zero-init

      unsigned long long key =
          ((unsigned long long)__float_as_uint(pr) << 32) | (unsigned)(~e);
      mk = key > mk ? key : mk;
    }
  }

#pragma unroll
  for (int off = 32; off; off >>= 1) {
    unsigned long long o = __shfl_xor(mk, off, 64);
    mk = o > mk ? o : mk;
  }
  if ((t & 63) == 0) wmax[t >> 6] = mk;
  __syncthreads();
  if (t == 0) {
    unsigned long long m = wmax[0];
#pragma unroll
    for (int i = 1; i < 4; ++i) m = wmax[i] > m ? wmax[i] : m;
    blockmax[h * 128 + blockIdx.y * gridDim.x + blockIdx.x] = m;
  }
}

// ---------------- fused top-k: inline threshold + compact + last-block finish
__global__ __launch_bounds__(512) void topk_fused(
    const float* __restrict__ prob, const unsigned long long* __restrict__ blockmax,
    unsigned* __restrict__ cnt, unsigned* __restrict__ done,
    unsigned long long* __restrict__ cand, float* __restrict__ sparse) {
  __shared__ unsigned long long keys[512];
  __shared__ unsigned long long thrS;
  __shared__ unsigned tkS;
  const int t = threadIdx.x, h = blockIdx.y, blk = blockIdx.x;

  // phase 1: threshold = 64th-largest of the 128 block maxes (exact; keys unique)
  if (t < 128) keys[t] = blockmax[h * 128 + t];
  __syncthreads();
  if (t < 128) {
    unsigned long long my = keys[t];
    int rank = 0;
    for (int j = 0; j < 128; ++j) rank += (keys[j] > my);
    if (rank == 63) thrS = my;     // guaranteed <= true 64th-largest element key
  }
  __syncthreads();
  const unsigned long long thr = thrS;

  // phase 2: scan this block's 4096 probs (8/thread, coalesced float4)
  const unsigned seg = (unsigned)blk * 4096u;
#pragma unroll
  for (int i = 0; i < 2; ++i) {
    const unsigned e0 = seg + (unsigned)i * 2048u + (unsigned)t * 4u;
    float4 p = *(const float4*)(prob + (unsigned)h * E_ + e0);
    float pv[4] = {p.x, p.y, p.z, p.w};
#pragma unroll
    for (int k2 = 0; k2 < 4; ++k2) {
      unsigned e = e0 + (unsigned)k2;
      unsigned long long key =
          ((unsigned long long)__float_as_uint(pv[k2]) << 32) | (unsigned)(~e);
      if (key >= thr) {
        unsigned pos = atomicAdd(&cnt[h], 1u);    // expected total ~177 << 512
        if (pos < 512u) cand[h * 512 + pos] = key;
      }
    }
  }
  __syncthreads();
  if (t == 0) { __threadfence(); tkS = atomicAdd(&done[h], 1u); }  // release
  __syncthreads();

  // phase 3: last block per head sorts candidates, scatters 64 ones
  if (tkS == 63u) {
    if (t == 0) __threadfence();                  // acquire (L1/L2 inv)
    __syncthreads();
    unsigned n = atomicAdd(&cnt[h], 0u);          // coherent read of final count
    if (n > 512u) n = 512u;
    keys[t] = (t < (int)n) ? cand[h * 512 + t] : 0ull;
    __syncthreads();
    for (int k = 2; k <= 512; k <<= 1)
      for (int j = k >> 1; j > 0; j >>= 1) {
        int ixj = t ^ j;
        if (ixj > t) {
          unsigned long long a = keys[t], b = keys[ixj];
          bool up = (t & k) == 0;
          if ((a > b) == up) { keys[t] = b; keys[ixj] = a; }
        }
        __syncthreads();
      }
    if (t >= 448) {                               // top 64 of ascending sort
      unsigned e = ~(unsigned)(keys[t] & 0xFFFFFFFFull);
      if (e < (unsigned)E_) sparse[(unsigned)h * E_ + e] = 1.0f;
    }
  }
}

extern "C" void kernel_launch(void* const* d_in, const int* in_sizes, int n_in,
                              void* d_out, int out_size, void* d_ws, size_t ws_size,
                              hipStream_t stream) {
  const float* feats = (const float*)d_in[0];
  const float* W_out = (const float*)d_in[1];
  const float* b_out = (const float*)d_in[2];
  const float* W_cat = (const float*)d_in[3];
  const float* b_cat = (const float*)d_in[4];
  float* out = (float*)d_out;

  // workspace: A | B | blockmax | cand | cnt | done
  float* A = (float*)d_ws;
  float* B = A + H_ * N_ * D_;
  unsigned long long* blockmax = (unsigned long long*)(B + H_ * N_ * D_);
  unsigned long long* cand = blockmax + H_ * 128;
  unsigned* cnt = (unsigned*)(cand + H_ * 512);
  unsigned* done = cnt + H_;

  precompute_ab<<<dim3(H_ * N_ / 4), dim3(256), 0, stream>>>(feats, W_out, A, B,
                                                             cnt, done);
  edge_kernel<<<dim3(N_ / 128, N_ / 16, H_), dim3(256), 0, stream>>>(
      A, B, b_out, W_cat, b_cat, out, blockmax);
  topk_fused<<<dim3(64, H_), dim3(512), 0, stream>>>(out + HE_, blockmax, cnt,
                                                     done, cand, out + 2 * HE_);
}

// Round 5
// 107.821 us; speedup vs baseline: 1.3250x; 1.0276x over previous
//
#include <hip/hip_runtime.h>
#include <stdint.h>

#define H_ 4
#define N_ 512
#define D_ 64
#define E_ (N_ * N_)        // 262144 edges per head
#define HE_ (H_ * E_)       // 1048576
#define EPS_ 1e-10f

// Partitionable threefry (verified rounds 1-3): counter (hi=0, lo=j), out = x0^x1.
__device__ __forceinline__ void tf2x32(unsigned x0, unsigned x1,
                                       unsigned& o0, unsigned& o1) {
  const unsigned ks0 = 0u;          // key hi of seed 42
  const unsigned ks1 = 42u;         // key lo
  const unsigned ks2 = 0x1BD11BDAu ^ ks0 ^ ks1;
  x0 += ks0; x1 += ks1;
#define TFR(r) { x0 += x1; x1 = (x1 << (r)) | (x1 >> (32 - (r))); x1 ^= x0; }
  TFR(13) TFR(15) TFR(26) TFR(6)
  x0 += ks1; x1 += ks2 + 1u;
  TFR(17) TFR(29) TFR(16) TFR(24)
  x0 += ks2; x1 += ks0 + 2u;
  TFR(13) TFR(15) TFR(26) TFR(6)
  x0 += ks0; x1 += ks1 + 3u;
  TFR(17) TFR(29) TFR(16) TFR(24)
  x0 += ks1; x1 += ks2 + 4u;
  TFR(13) TFR(15) TFR(26) TFR(6)
  x0 += ks2; x1 += ks0 + 5u;
#undef TFR
  o0 = x0; o1 = x1;
}

__device__ __forceinline__ unsigned rng_bits(unsigned j) {
  unsigned a, b;
  tf2x32(0u, j, a, b);
  return a ^ b;
}

__device__ __forceinline__ float u01(unsigned bits) {
  return __uint_as_float((bits >> 9) | 0x3f800000u) - 1.0f;
}

// ---------------- node projection + zero-init of topk control words
__global__ __launch_bounds__(256) void precompute_ab(
    const float* __restrict__ feats, const float* __restrict__ W_out,
    float* __restrict__ A, float* __restrict__ B,
    unsigned* __restrict__ cnt, unsigned* __restrict__ done) {
  int row = blockIdx.x * 4 + (threadIdx.x >> 6);   // h*N + n
  int d = threadIdx.x & 63;
  if (blockIdx.x == 0) {            // ws is poisoned 0xAA each call: zero control
    if (threadIdx.x < 4) cnt[threadIdx.x] = 0u;
    else if (threadIdx.x < 8) done[threadIdx.x - 4] = 0u;
  }
  __shared__ float f[4][64];
  f[threadIdx.x >> 6][d] = feats[row * D_ + d];
  __syncthreads();
  const float* fr = f[threadIdx.x >> 6];
  float a = 0.f, b = 0.f;
#pragma unroll 8
  for (int k = 0; k < D_; ++k) {
    float fv = fr[k];
    a = fmaf(fv, W_out[k * D_ + d], a);          // sender rows [0,64)
    b = fmaf(fv, W_out[(k + D_) * D_ + d], b);   // receiver rows [64,128)
  }
  A[row * D_ + d] = a;
  B[row * D_ + d] = b;
}

// ---------------- edge kernel: 64 snd x 16 rec tile, 4 edges/thread.
// LDS ~22 KB, launch_bounds(256,4) -> 4 blocks/CU (vs 2 at the 128-tile):
// doubles resident waves to hide the threefry/logf serial chains.
__global__ __launch_bounds__(256, 4) void edge_kernel(
    const float* __restrict__ A, const float* __restrict__ B,
    const float* __restrict__ b_out, const float* __restrict__ W_cat,
    const float* __restrict__ b_cat, float* __restrict__ out,
    unsigned long long* __restrict__ blockmax) {
  __shared__ __align__(16) float Ash[64][68];   // stride 68: rows 16B-aligned
  __shared__ __align__(16) float Bsh[16][64];
  __shared__ float4 bsh4[16];
  __shared__ float4 wc4[32];
  __shared__ float bc2[2];
  __shared__ unsigned long long wmax[4];

  const int t = threadIdx.x;
  const int h = blockIdx.z;
  const int snd_base = blockIdx.x * 64;
  const int rec_base = blockIdx.y * 16;

  {
    const float4* A4 = (const float4*)(A + (h * N_ + snd_base) * D_);
    for (int i = t; i < 1024; i += 256)          // 64 rows x 16 float4
      *(float4*)&Ash[i >> 4][(i & 15) << 2] = A4[i];
    const float4* B4 = (const float4*)(B + (h * N_ + rec_base) * D_);
    *(float4*)&Bsh[t >> 4][(t & 15) << 2] = B4[t];
  }
  if (t < 16) bsh4[t] = ((const float4*)b_out)[t];
  else if (t < 48) wc4[t - 16] = ((const float4*)W_cat)[t - 16];
  else if (t == 48) { bc2[0] = b_cat[0]; bc2[1] = b_cat[1]; }
  __syncthreads();

  const int s = t & 63;            // sender lane (per-lane varying)
  const int rg = (t >> 6) * 4;     // receiver group (wave-uniform)

  float l0[4], l1[4];
#pragma unroll
  for (int r = 0; r < 4; ++r) { l0[r] = 0.f; l1[r] = 0.f; }

  // Per edge the fp chain is EXACTLY: for d=0..63 { t=relu((A+B)+b); l=fma(t,w,l) }
#pragma unroll
  for (int d4 = 0; d4 < 16; ++d4) {
    const float4 a0 = *(const float4*)&Ash[s][d4 << 2];
    const float4 bd = bsh4[d4];
    const float4 wA = wc4[2 * d4];
    const float4 wB = wc4[2 * d4 + 1];
#pragma unroll
    for (int r = 0; r < 4; ++r) {
      const float4 bv = *(const float4*)&Bsh[rg + r][d4 << 2];
      float t0;
      t0 = fmaxf((a0.x + bv.x) + bd.x, 0.f);
      l0[r] = fmaf(t0, wA.x, l0[r]); l1[r] = fmaf(t0, wA.y, l1[r]);
      t0 = fmaxf((a0.y + bv.y) + bd.y, 0.f);
      l0[r] = fmaf(t0, wA.z, l0[r]); l1[r] = fmaf(t0, wA.w, l1[r]);
      t0 = fmaxf((a0.z + bv.z) + bd.z, 0.f);
      l0[r] = fmaf(t0, wB.x, l0[r]); l1[r] = fmaf(t0, wB.y, l1[r]);
      t0 = fmaxf((a0.w + bv.w) + bd.w, 0.f);
      l0[r] = fmaf(t0, wB.z, l0[r]); l1[r] = fmaf(t0, wB.w, l1[r]);
    }
  }

  unsigned long long mk = 0ull;
#pragma unroll
  for (int r = 0; r < 4; ++r) {
    float L0 = l0[r] + bc2[0];
    float L1 = l1[r] + bc2[1];
    const unsigned snd = (unsigned)(snd_base + s);
    const unsigned rec = (unsigned)(rec_base + rg + r);
    const unsigned e = rec * (unsigned)N_ + snd;
    const unsigned base = ((unsigned)h << 18) + e;
    const unsigned j0 = base * 2u;

    float uu0 = u01(rng_bits(j0));
    float uu1 = u01(rng_bits(j0 + 1u));
    float g0 = -logf(-logf(uu0 + EPS_) + EPS_);
    float g1 = -logf(-logf(uu1 + EPS_) + EPS_);

    // argmax(softmax((l+g)/0.5)) == (L1+g1 > L0+g0): /0.5 exact, softmax monotone
    float cm = ((L1 + g1) > (L0 + g0)) ? 1.0f : 0.0f;

    float lm = fmaxf(L0, L1);
    float p0 = expf(L0 - lm), p1 = expf(L1 - lm);
    float pr = p1 / (p0 + p1);

    out[base] = cm;
    out[HE_ + base] = pr;
    out[2 * HE_ + base] = 0.f;     // sparse_labels zero-init (winners set later)

    unsigned long long key =
        ((unsigned long long)__float_as_uint(pr) << 32) | (unsigned)(~e);
    mk = key > mk ? key : mk;
  }

#pragma unroll
  for (int off = 32; off; off >>= 1) {
    unsigned long long o = __shfl_xor(mk, off, 64);
    mk = o > mk ? o : mk;
  }
  if ((t & 63) == 0) wmax[t >> 6] = mk;
  __syncthreads();
  if (t == 0) {
    unsigned long long m = wmax[0];
#pragma unroll
    for (int i = 1; i < 4; ++i) m = wmax[i] > m ? wmax[i] : m;
    blockmax[h * 256 + blockIdx.y * gridDim.x + blockIdx.x] = m;  // 256 chunks/head
  }
}

// ---------------- fused top-k: inline threshold + compact + last-block finish
__global__ __launch_bounds__(512) void topk_fused(
    const float* __restrict__ prob, const unsigned long long* __restrict__ blockmax,
    unsigned* __restrict__ cnt, unsigned* __restrict__ done,
    unsigned long long* __restrict__ cand, float* __restrict__ sparse) {
  __shared__ unsigned long long keys[512];
  __shared__ unsigned long long thrS;
  __shared__ unsigned tkS;
  const int t = threadIdx.x, h = blockIdx.y, blk = blockIdx.x;

  // phase 1: threshold = 64th-largest of the 256 chunk maxes (exact; keys unique)
  if (t < 256) keys[t] = blockmax[h * 256 + t];
  __syncthreads();
  if (t < 256) {
    unsigned long long my = keys[t];
    int rank = 0;
    for (int j = 0; j < 256; ++j) rank += (keys[j] > my);
    if (rank == 63) thrS = my;     // guaranteed <= true 64th-largest element key
  }
  __syncthreads();
  const unsigned long long thr = thrS;

  // phase 2: scan this block's 4096 probs (8/thread, coalesced float4)
  const unsigned seg = (unsigned)blk * 4096u;
#pragma unroll
  for (int i = 0; i < 2; ++i) {
    const unsigned e0 = seg + (unsigned)i * 2048u + (unsigned)t * 4u;
    float4 p = *(const float4*)(prob + (unsigned)h * E_ + e0);
    float pv[4] = {p.x, p.y, p.z, p.w};
#pragma unroll
    for (int k2 = 0; k2 < 4; ++k2) {
      unsigned e = e0 + (unsigned)k2;
      unsigned long long key =
          ((unsigned long long)__float_as_uint(pv[k2]) << 32) | (unsigned)(~e);
      if (key >= thr) {
        unsigned pos = atomicAdd(&cnt[h], 1u);    // expected total ~155 << 512
        if (pos < 512u) cand[h * 512 + pos] = key;
      }
    }
  }
  __syncthreads();
  if (t == 0) { __threadfence(); tkS = atomicAdd(&done[h], 1u); }  // release
  __syncthreads();

  // phase 3: last block per head sorts candidates, scatters 64 ones
  if (tkS == 63u) {
    if (t == 0) __threadfence();                  // acquire
    __syncthreads();
    unsigned n = atomicAdd(&cnt[h], 0u);          // coherent read of final count
    if (n > 512u) n = 512u;
    keys[t] = (t < (int)n) ? cand[h * 512 + t] : 0ull;
    __syncthreads();
    for (int k = 2; k <= 512; k <<= 1)
      for (int j = k >> 1; j > 0; j >>= 1) {
        int ixj = t ^ j;
        if (ixj > t) {
          unsigned long long a = keys[t], b = keys[ixj];
          bool up = (t & k) == 0;
          if ((a > b) == up) { keys[t] = b; keys[ixj] = a; }
        }
        __syncthreads();
      }
    if (t >= 448) {                               // top 64 of ascending sort
      unsigned e = ~(unsigned)(keys[t] & 0xFFFFFFFFull);
      if (e < (unsigned)E_) sparse[(unsigned)h * E_ + e] = 1.0f;
    }
  }
}

extern "C" void kernel_launch(void* const* d_in, const int* in_sizes, int n_in,
                              void* d_out, int out_size, void* d_ws, size_t ws_size,
                              hipStream_t stream) {
  const float* feats = (const float*)d_in[0];
  const float* W_out = (const float*)d_in[1];
  const float* b_out = (const float*)d_in[2];
  const float* W_cat = (const float*)d_in[3];
  const float* b_cat = (const float*)d_in[4];
  float* out = (float*)d_out;

  // workspace: A | B | blockmax | cand | cnt | done
  float* A = (float*)d_ws;
  float* B = A + H_ * N_ * D_;
  unsigned long long* blockmax = (unsigned long long*)(B + H_ * N_ * D_);
  unsigned long long* cand = blockmax + H_ * 256;
  unsigned* cnt = (unsigned*)(cand + H_ * 512);
  unsigned* done = cnt + H_;

  precompute_ab<<<dim3(H_ * N_ / 4), dim3(256), 0, stream>>>(feats, W_out, A, B,
                                                             cnt, done);
  edge_kernel<<<dim3(N_ / 64, N_ / 16, H_), dim3(256), 0, stream>>>(
      A, B, b_out, W_cat, b_cat, out, blockmax);
  topk_fused<<<dim3(64, H_), dim3(512), 0, stream>>>(out + HE_, blockmax, cnt,
                                                     done, cand, out + 2 * HE_);
}